// Round 8
// baseline (28.132 us; speedup 1.0000x reference)
//
#include <hip/hip_runtime.h>

#define NCH   256
#define FH    64
#define FW    64
#define OUT_H 7
#define OUT_W 7
#define WPB   2      // waves per block
#define CPW   2      // channels per wave (same ROI -> shared scalar work)
#define MAXH  34     // max region rows
#define LDSW  40     // floats per LDS row (10 quads)

__global__ __launch_bounds__(128) void roipool_kernel(
    const float* __restrict__ fm,   // (B, C, H, W)
    const int*   __restrict__ rois, // (N, 5): b, x1, y1, x2, y2
    float*       __restrict__ out)  // (N, C, 7, 7)
{
    __shared__ __align__(16) float lds[WPB][CPW][MAXH][LDSW];  // 21760 B

    const int tid  = threadIdx.x;
    const int wv   = tid >> 6;
    const int lane = tid & 63;
    // wave task-pair id: covers channels 2*cp, 2*cp+1 of roi n
    const int t2 = __builtin_amdgcn_readfirstlane(blockIdx.x * WPB + wv);
    const int n  = t2 >> 7;
    const int c0 = (t2 & 127) * 2;

    const int* r = rois + n * 5;    // scalar loads (t2 uniform)
    const int b  = r[0];
    const int x1 = r[1] >> 4;       // exact: x*(1/16.f) trunc, 0<=x<1024
    const int y1 = r[2] >> 4;
    const int x2 = r[3] >> 4;
    const int y2 = r[4] >> 4;
    const int h_roi = y2 - y1 + 1;  // 1..34
    const int w_roi = x2 - x1 + 1;  // 1..34, bins never empty
    const int qs  = x1 >> 2;        // first aligned quad of region rows
    const int qn  = (x2 >> 2) - qs + 1;   // quads per row, 1..10
    const int off = x1 & 3;         // LDS col of x1

    // Tight SCALAR band-span bounds: max span = q + T[r], T={0,1,2,2,2,2,2}
    const int hq = h_roi / 7, hr = h_roi - hq * 7;
    const int wq = w_roi / 7, wr = w_roi - wq * 7;
    const int hb  = hq + (hr == 0 ? 0 : (hr == 1 ? 1 : 2));   // 1..6
    const int wbn = wq + (wr == 0 ? 0 : (wr == 1 ? 1 : 2));   // 1..6

    // ---- stage both channels: lane -> (row-group rr, quad qq) ----
    const int rg = lane / 10;            // 0..6
    const int rr = (rg == 6) ? 0 : rg;   // lanes 60..63 duplicate (benign)
    const int qq = lane - rg * 10;       // 0..9 (0..3 for lanes 60..63)
    const int passes = (h_roi + 5) / 6;  // scalar trip, 1..6

    const float4* srcq0 =
        (const float4*)(fm + (((size_t)(b * NCH + c0)) << 12) + ((size_t)y1 << 6)) + qs;
    const float4* srcq1 = srcq0 + (1 << 10);   // next channel: 4096 floats = 1024 float4
    const bool qok = (qq < qn);
    for (int p = 0; p < passes; ++p) {   // scalar trip
        int hh = rr + p * 6;
        hh = (hh < h_roi) ? hh : (h_roi - 1);   // clamp: dup re-write, same data
        if (qok) {
            const float4 v0 = srcq0[hh * (FW / 4) + qq];  // independent loads,
            const float4 v1 = srcq1[hh * (FW / 4) + qq];  // batched in flight
            ((float4*)&lds[wv][0][hh][0])[qq] = v0;
            ((float4*)&lds[wv][1][hh][0])[qq] = v1;
        }
    }
    // no barrier: same wave produces and consumes its LDS slice (lgkmcnt orders)

    // ---- compute: lane = cell; scalar-guarded clamped reads, 2 channels ----
    if (lane < OUT_H * OUT_W) {
        const int i = lane / OUT_W;
        const int j = lane - i * OUT_W;

        const int hs  = (i * h_roi) / OUT_H;
        const int he1 = ((i + 1) * h_roi + 6) / OUT_H - 1;        // last row
        const int ws  = (j * w_roi) / OUT_W + off;
        const int we1 = ((j + 1) * w_roi + 6) / OUT_W - 1 + off;  // last col

        int cb[6];                      // clamped cols, compile-time indexed
        #pragma unroll
        for (int bb = 0; bb < 6; ++bb) {
            const int w = ws + bb;
            cb[bb] = (w < we1) ? w : we1;
        }

        const float* tb0 = &lds[wv][0][0][0];
        const float* tb1 = &lds[wv][1][0][0];
        float m0 = -INFINITY, m1 = -INFINITY;
        #pragma unroll
        for (int a = 0; a < 6; ++a) {
            if (a < hb) {                            // SCALAR guard (sgpr hb)
                const int hh = (hs + a < he1) ? hs + a : he1;   // lane clamp
                const float* rp0 = tb0 + hh * LDSW;
                const float* rp1 = tb1 + hh * LDSW;
                #pragma unroll
                for (int bb = 0; bb < 6; ++bb) {
                    if (bb < wbn) {                  // SCALAR guard (sgpr wbn)
                        m0 = fmaxf(m0, rp0[cb[bb]]);
                        m1 = fmaxf(m1, rp1[cb[bb]]);
                    }
                }
            }
        }
        float* o = out + (size_t)(n * NCH + c0) * (OUT_H * OUT_W) + lane;
        o[0]             = m0;                       // 392 B contiguous per wave
        o[OUT_H * OUT_W] = m1;
    }
}

extern "C" void kernel_launch(void* const* d_in, const int* in_sizes, int n_in,
                              void* d_out, int out_size, void* d_ws, size_t ws_size,
                              hipStream_t stream) {
    const float* fm   = (const float*)d_in[0];
    const int*   rois = (const int*)d_in[1];
    float*       out  = (float*)d_out;

    const int N = in_sizes[1] / 5;            // 256 rois
    dim3 grid((N * NCH) / (WPB * CPW));       // 16384 blocks
    dim3 block(WPB * 64);                     // 128 threads
    roipool_kernel<<<grid, block, 0, stream>>>(fm, rois, out);
}

// Round 9
// 27.021 us; speedup vs baseline: 1.0411x; 1.0411x over previous
//
#include <hip/hip_runtime.h>

#define NCH   256
#define FH    64
#define FW    64
#define OUT_H 7
#define OUT_W 7
#define WPB   4      // independent waves per block
#define MAXH  34     // max region rows
#define LDSW  40     // floats per LDS row (10 quads)

__global__ __launch_bounds__(256) void roipool_kernel(
    const float* __restrict__ fm,   // (B, C, H, W)
    const int*   __restrict__ rois, // (N, 5): b, x1, y1, x2, y2
    float*       __restrict__ out)  // (N, C, 7, 7)
{
    __shared__ __align__(16) float lds[WPB][MAXH][LDSW];  // 21760 B

    const int tid  = threadIdx.x;
    const int wv   = tid >> 6;
    const int lane = tid & 63;
    const int task = __builtin_amdgcn_readfirstlane(blockIdx.x * WPB + wv);
    const int n    = task >> 8;
    const int c    = task & 255;

    const int* r = rois + n * 5;    // scalar loads (task uniform)
    const int b  = r[0];
    const int x1 = r[1] >> 4;       // exact: x*(1/16.f) trunc, 0<=x<1024
    const int y1 = r[2] >> 4;
    const int x2 = r[3] >> 4;
    const int y2 = r[4] >> 4;
    const int h_roi = y2 - y1 + 1;  // 1..34
    const int w_roi = x2 - x1 + 1;  // 1..34, bins never empty
    const int qs  = x1 >> 2;        // first aligned quad of region rows
    const int qn  = (x2 >> 2) - qs + 1;   // quads per row, 1..10
    const int off = x1 & 3;         // LDS col of x1

    // Tight SCALAR band-span bounds: max span = q + T[r], T={0,1,2,2,2,2,2}
    const int hq = h_roi / 7, hr = h_roi - hq * 7;
    const int wq = w_roi / 7, wr = w_roi - wq * 7;
    const int hb  = hq + (hr == 0 ? 0 : (hr == 1 ? 1 : 2));   // 1..6
    const int wbn = wq + (wr == 0 ? 0 : (wr == 1 ? 1 : 2));   // 1..6

    // ---- stage: lane -> (row-group rr 0..5, quad qq 0..9) ----
    // ALL loads issued into registers first (one latency exposure), then writes.
    const int rg = lane / 10;            // 0..6
    const int rr = (rg == 6) ? 0 : rg;   // lanes 60..63 duplicate (benign)
    const int qq = lane - rg * 10;       // 0..9 (0..3 for lanes 60..63)
    const int passes = (h_roi + 5) / 6;  // scalar, 1..6

    const float4* srcq =
        (const float4*)(fm + (((size_t)(b * NCH + c)) << 12) + ((size_t)y1 << 6)) + qs;
    const bool qok = (qq < qn);

    float4 v0, v1, v2, v3, v4, v5;       // staged quads (conditionally live)
    int h0, h1, h2, h3, h4, h5;
    if (qok) {
        // clamped row index per pass; dup loads/writes benign (same data)
        h0 = rr;                                   // p=0 always
        v0 = srcq[h0 * (FW / 4) + qq];
        if (passes > 1) { h1 = rr + 6;  h1 = (h1 < h_roi) ? h1 : (h_roi - 1); v1 = srcq[h1 * (FW / 4) + qq]; }
        if (passes > 2) { h2 = rr + 12; h2 = (h2 < h_roi) ? h2 : (h_roi - 1); v2 = srcq[h2 * (FW / 4) + qq]; }
        if (passes > 3) { h3 = rr + 18; h3 = (h3 < h_roi) ? h3 : (h_roi - 1); v3 = srcq[h3 * (FW / 4) + qq]; }
        if (passes > 4) { h4 = rr + 24; h4 = (h4 < h_roi) ? h4 : (h_roi - 1); v4 = srcq[h4 * (FW / 4) + qq]; }
        if (passes > 5) { h5 = rr + 30; h5 = (h5 < h_roi) ? h5 : (h_roi - 1); v5 = srcq[h5 * (FW / 4) + qq]; }

        float4* ldsq = (float4*)&lds[wv][0][0];
        ldsq[h0 * (LDSW / 4) + qq] = v0;
        if (passes > 1) ldsq[h1 * (LDSW / 4) + qq] = v1;
        if (passes > 2) ldsq[h2 * (LDSW / 4) + qq] = v2;
        if (passes > 3) ldsq[h3 * (LDSW / 4) + qq] = v3;
        if (passes > 4) ldsq[h4 * (LDSW / 4) + qq] = v4;
        if (passes > 5) ldsq[h5 * (LDSW / 4) + qq] = v5;
    }
    // no barrier: same wave produces and consumes its LDS slice (lgkmcnt orders)

    // ---- compute: lane = cell; scalar-trip clamped reads (avg ~4x4, max 6x6) ----
    if (lane < OUT_H * OUT_W) {
        const int i = lane / OUT_W;
        const int j = lane - i * OUT_W;

        const int hs  = (i * h_roi) / OUT_H;
        const int he1 = ((i + 1) * h_roi + 6) / OUT_H - 1;        // last row
        const int ws  = (j * w_roi) / OUT_W + off;
        const int we1 = ((j + 1) * w_roi + 6) / OUT_W - 1 + off;  // last col

        int cb[6];                      // clamped cols, compile-time indexed
        #pragma unroll
        for (int bb = 0; bb < 6; ++bb) {
            const int w = ws + bb;
            cb[bb] = (w < we1) ? w : we1;
        }

        const float* tb = &lds[wv][0][0];
        float m = -INFINITY;
        #pragma unroll
        for (int a = 0; a < 6; ++a) {
            if (a < hb) {                            // SCALAR guard (sgpr hb)
                const int hh = (hs + a < he1) ? hs + a : he1;   // lane clamp
                const float* rp = tb + hh * LDSW;
                #pragma unroll
                for (int bb = 0; bb < 6; ++bb) {
                    if (bb < wbn)                    // SCALAR guard (sgpr wbn)
                        m = fmaxf(m, rp[cb[bb]]);
                }
            }
        }
        out[(size_t)task * (OUT_H * OUT_W) + lane] = m;  // 196 B contiguous/wave
    }
}

extern "C" void kernel_launch(void* const* d_in, const int* in_sizes, int n_in,
                              void* d_out, int out_size, void* d_ws, size_t ws_size,
                              hipStream_t stream) {
    const float* fm   = (const float*)d_in[0];
    const int*   rois = (const int*)d_in[1];
    float*       out  = (float*)d_out;

    const int N = in_sizes[1] / 5;            // 256 rois
    dim3 grid((N * NCH) / WPB);               // 16384 blocks
    dim3 block(256);
    roipool_kernel<<<grid, block, 0, stream>>>(fm, rois, out);
}